// Round 14
// baseline (187.173 us; speedup 1.0000x reference)
//
#include <hip/hip_runtime.h>
#include <hip/hip_bf16.h>

// MHA: B=2, S=4096, E=512, H=8, D=64. fp32 in/out, bf16 MFMA internally.
// ws (shorts): XB/O [8192*512] | WB [4*512*512] | Q | K | VT
// Q pre-scaled by log2(e)/sqrt(D).
// R14 attn: R5's wq x wt decomposition (q-tile 128; 4 waves = 2 q-groups
// (W_q=64, mi=0..3) x 2 t-halves) -- the ONLY decomposition that halves
// per-CU LDS reads (8 b128/wave/tile vs 16) at unchanged block count --
// now with R3's BATCHED phases (all QK -> all exp -> all PV; R5 serialized
// per-mi and lost 11us to dependency chains) and R8's counted-vmcnt
// schedule. Per wave per 64-t tile: 36 MFMA, 8 b128, 32 exp2.
// Cross-wt O/psum reduce at end aliases staging (R5-validated numerics).
// Permuted K-row map within wt's 32-t half: tile T row m holds
// t = wt*32 + 8*(m>>2) + 4*T + (m&3) -> (T0,T1) = 16x16x32 A-frag ->
// full-rate K=32 PV. K LDS swizzle f(r)=(r&7)^((r>>2)&7); V chunk c^=(r&7).
// psum via ones-MFMA (row-sum replicated over l16; bias cancels in ratio).
// convert/qkv/outproj = R13/R10 verbatim (BK=64, counted vmcnt, LDS-pack /
// float4 epilogues). Ledger: R11 fusion -9us, R12 BK=32 -13us (reverted).

typedef __attribute__((ext_vector_type(8))) short short8;
typedef __attribute__((ext_vector_type(4))) short short4v;
typedef __attribute__((ext_vector_type(4))) float floatx4;
typedef __attribute__((ext_vector_type(2))) float floatx2;

#define SEQ 4096
#define EMB 512
#define NH 8
#define HD 64
#define MROWS 8192
#define SC2 0.18033688011112042f  // log2(e)/sqrt(64)

__device__ inline unsigned short f2bf_rne(float f) {
    union { float f; unsigned int u; } c; c.f = f;
    unsigned int u = c.u;
    return (unsigned short)((u + 0x7FFFu + ((u >> 16) & 1u)) >> 16);
}

__device__ inline short8 load8f(const float* __restrict__ p) {
    float4 a = *(const float4*)p;
    float4 b = *(const float4*)(p + 4);
    short8 r;
    r[0] = (short)f2bf_rne(a.x); r[1] = (short)f2bf_rne(a.y);
    r[2] = (short)f2bf_rne(a.z); r[3] = (short)f2bf_rne(a.w);
    r[4] = (short)f2bf_rne(b.x); r[5] = (short)f2bf_rne(b.y);
    r[6] = (short)f2bf_rne(b.z); r[7] = (short)f2bf_rne(b.w);
    return r;
}

__device__ inline void gload_lds16(const unsigned short* g, unsigned short* l) {
    __builtin_amdgcn_global_load_lds(
        (__attribute__((address_space(1))) void*)(void*)g,
        (__attribute__((address_space(3))) void*)l,
        16, 0, 0);
}

// pack 2 f32 -> 2 bf16, round-half-up (epilogue-quality)
__device__ inline unsigned int pk_bf2(float a, float b) {
    union { float f; unsigned int u; } ca, cb; ca.f = a; cb.f = b;
    return __builtin_amdgcn_perm(cb.u + 0x8000u, ca.u + 0x8000u, 0x07060302u);
}

// pack 2 f32 -> 2 bf16, truncating (P-matrix: positive values, <=0.2% bias)
__device__ inline unsigned int pk_bf2t(float a, float b) {
    union { float f; unsigned int u; } ca, cb; ca.f = a; cb.f = b;
    return __builtin_amdgcn_perm(cb.u, ca.u, 0x07060302u);
}

// ---------------- fp32 -> bf16 pre-convert ----------------
__global__ __launch_bounds__(256) void convert_kernel(
    const float* __restrict__ x, const float* __restrict__ Wq,
    const float* __restrict__ Wk, const float* __restrict__ Wv,
    const float* __restrict__ Wo, unsigned short* __restrict__ xb,
    unsigned short* __restrict__ wb)
{
    const size_t i8 = ((size_t)blockIdx.x * 256 + threadIdx.x) * 8;
    const float* src; unsigned short* dst;
    if (i8 < (size_t)MROWS * EMB) { src = x + i8; dst = xb + i8; }
    else {
        size_t j = i8 - (size_t)MROWS * EMB;
        int w = (int)(j >> 18); size_t off = j & 262143;
        src = (w == 0 ? Wq : w == 1 ? Wk : w == 2 ? Wv : Wo) + off;
        dst = wb + (size_t)w * 262144 + off;
    }
    *(short8*)dst = load8f(src);
}

// ---------------- QKV projection, 128x128, BK=64, dbuf, counted vmcnt ----------------
// z=0 -> Q [b,h,s,d] scaled SC2; z=1 -> K [b,h,s,d]; z=2 -> V^T [b,h,d,s]
__global__ __launch_bounds__(256) void qkv_kernel(
    const unsigned short* __restrict__ xb, const unsigned short* __restrict__ wb,
    const float* __restrict__ bq, const float* __restrict__ bk,
    const float* __restrict__ bv, unsigned short* __restrict__ Qo,
    unsigned short* __restrict__ Ko, unsigned short* __restrict__ VTo)
{
    __shared__ unsigned short smem[32768];  // sA[2][8192] | sB[2][8192]; epilogue ct aliases

    const int tid = threadIdx.x, wave = tid >> 6, lane = tid & 63;
    const int quad = lane >> 4, l16 = lane & 15;
    const int wm = wave >> 1, wn = wave & 1;
    const int row0 = blockIdx.x * 128, col0 = blockIdx.y * 128;
    const int z = blockIdx.z;

    unsigned short* sA = smem;
    unsigned short* sB = smem + 16384;

    const unsigned short* A = xb + (size_t)row0 * EMB;
    const unsigned short* Bm = wb + (size_t)z * 262144 + (size_t)col0 * EMB;
    const float* bias = z == 0 ? bq : z == 1 ? bk : bv;
    unsigned short* out = z == 0 ? Qo : z == 1 ? Ko : VTo;

    // issues exactly 8 gload_lds per thread -> vmcnt counts 8 per stage
    auto stage = [&](int buf, int k0) {
#pragma unroll
        for (int it = 0; it < 4; ++it) {
            const int s = it * 256 + tid;
            const int row = s >> 3, cg = (s & 7) ^ (row & 7);
            const size_t go = (size_t)row * EMB + k0 + cg * 8;
            gload_lds16(A + go, &sA[buf * 8192 + (it * 256 + wave * 64) * 8]);
            gload_lds16(Bm + go, &sB[buf * 8192 + (it * 256 + wave * 64) * 8]);
        }
    };

    floatx4 acc[4][4];
#pragma unroll
    for (int i = 0; i < 4; ++i)
#pragma unroll
        for (int j = 0; j < 4; ++j) { floatx4 zz = {0.f,0.f,0.f,0.f}; acc[i][j] = zz; }

    stage(0, 0);
    int buf = 0;
    for (int k0 = 0; k0 < EMB; k0 += 64) {
        __builtin_amdgcn_s_barrier();
        __builtin_amdgcn_sched_barrier(0);
        if (k0 + 64 < EMB) {
            stage(buf ^ 1, k0 + 64);
            asm volatile("s_waitcnt vmcnt(8)" ::: "memory");
        } else {
            asm volatile("s_waitcnt vmcnt(0)" ::: "memory");
        }
        __builtin_amdgcn_s_barrier();
        __builtin_amdgcn_sched_barrier(0);
#pragma unroll
        for (int kk = 0; kk < 2; ++kk) {
            short8 a[4], b[4];
#pragma unroll
            for (int mi = 0; mi < 4; ++mi)
                a[mi] = *(const short8*)&sA[buf * 8192 + (wm * 64 + mi * 16 + l16) * 64 + (((kk * 4 + quad) ^ (l16 & 7)) << 3)];
#pragma unroll
            for (int ni = 0; ni < 4; ++ni)
                b[ni] = *(const short8*)&sB[buf * 8192 + (wn * 64 + ni * 16 + l16) * 64 + (((kk * 4 + quad) ^ (l16 & 7)) << 3)];
            if (z != 2) {
                // swapped operands -> acc[i][j] = C^T block: rows n (i), cols m (j)
#pragma unroll
                for (int i = 0; i < 4; ++i)
#pragma unroll
                    for (int j = 0; j < 4; ++j)
                        acc[i][j] = __builtin_amdgcn_mfma_f32_16x16x32_bf16(b[i], a[j], acc[i][j], 0, 0, 0);
            } else {
#pragma unroll
                for (int i = 0; i < 4; ++i)
#pragma unroll
                    for (int j = 0; j < 4; ++j)
                        acc[i][j] = __builtin_amdgcn_mfma_f32_16x16x32_bf16(a[i], b[j], acc[i][j], 0, 0, 0);
            }
        }
        buf ^= 1;
    }

    // ---- epilogue: pack b64 into ct[row][132] then coalesced b128 stores ----
    __syncthreads();
    unsigned short* ct = smem;  // 128 x 132 shorts = 33.8 KB (aliases staging)
    const float qs = (z == 0) ? SC2 : 1.0f;
    if (z != 2) {
#pragma unroll
        for (int i = 0; i < 4; ++i) {
            const int n0 = wn * 64 + i * 16 + quad * 4;
            const float4 fb = *(const float4*)&bias[col0 + n0];
#pragma unroll
            for (int j = 0; j < 4; ++j) {
                const int m = wm * 64 + j * 16 + l16;
                ushort4 pk;
                pk.x = f2bf_rne((acc[i][j][0] + fb.x) * qs);
                pk.y = f2bf_rne((acc[i][j][1] + fb.y) * qs);
                pk.z = f2bf_rne((acc[i][j][2] + fb.z) * qs);
                pk.w = f2bf_rne((acc[i][j][3] + fb.w) * qs);
                *(ushort4*)&ct[m * 132 + n0] = pk;
            }
        }
    } else {
#pragma unroll
        for (int j = 0; j < 4; ++j) {
            const int n = wn * 64 + j * 16 + l16;
            const float fb = bias[col0 + n];
#pragma unroll
            for (int i = 0; i < 4; ++i) {
                const int m0 = wm * 64 + i * 16 + quad * 4;
                ushort4 pk;
                pk.x = f2bf_rne(acc[i][j][0] + fb);
                pk.y = f2bf_rne(acc[i][j][1] + fb);
                pk.z = f2bf_rne(acc[i][j][2] + fb);
                pk.w = f2bf_rne(acc[i][j][3] + fb);
                *(ushort4*)&ct[n * 132 + m0] = pk;
            }
        }
    }
    __syncthreads();
#pragma unroll
    for (int it = 0; it < 8; ++it) {
        const int idx = it * 256 + tid;
        const int row = idx >> 4, chunk = idx & 15;
        short8 v = *(const short8*)&ct[row * 132 + chunk * 8];
        size_t addr;
        if (z != 2) {
            const int m_g = row0 + row;
            const int b = m_g >> 12, s = m_g & 4095;
            const int n_g = col0 + chunk * 8;
            const int h = n_g >> 6, d = n_g & 63;
            addr = ((size_t)((b * NH + h) * SEQ + s)) * HD + d;
        } else {
            const int n_g = col0 + row;
            const int h = n_g >> 6, d = n_g & 63;
            const int m_g = row0 + chunk * 8;
            const int b = m_g >> 12, s0 = m_g & 4095;
            addr = ((size_t)((b * NH + h) * HD + d)) * SEQ + s0;
        }
        *(short8*)&out[addr] = v;
    }
}

// ---------------- flash attention: 2q x 2t waves, W_q=64, batched phases, counted vmcnt ----------------
// grid (bh, q-tile 128): same-bh blocks land on same XCD (stride 16 % 8 == 0) -> L2 reuse
__global__ __launch_bounds__(256, 2) void attn_kernel(
    const unsigned short* __restrict__ Q, const unsigned short* __restrict__ K,
    const unsigned short* __restrict__ VT, unsigned short* __restrict__ Oout)
{
    // staging: sK[buf] @ [buf*4096), sVT[buf] @ [8192+buf*4096) (shorts, 32KB)
    // cross-wt reduce aliases as float[8192]: per-wq 4096-float region
    __shared__ unsigned short smem[16384];
    __shared__ float sPS[128];  // [wq*64 + q] psum partials from wt=1

    const int tid = threadIdx.x, wave = tid >> 6, lane = tid & 63;
    const int quad = lane >> 4, l16 = lane & 15;
    const int wq = wave >> 1, wt = wave & 1;
    const int bh = blockIdx.x, q0 = blockIdx.y * 128;
    const int xm = l16 & 7;

    const unsigned short* Qh = Q + (size_t)bh * SEQ * HD;
    const unsigned short* Kh = K + (size_t)bh * SEQ * HD;
    const unsigned short* Vh = VT + (size_t)bh * HD * SEQ;

    // this wave's 64 q-rows (q-group wq), mi = 0..3
    short8 qf[4][2];  // [mi][kk]
#pragma unroll
    for (int mi = 0; mi < 4; ++mi)
#pragma unroll
        for (int kk = 0; kk < 2; ++kk)
            qf[mi][kk] = *(const short8*)(Qh + (size_t)(q0 + wq * 64 + mi * 16 + l16) * HD + kk * 32 + quad * 8);

    // permuted K-row map for t-half wt: tile T, A-row m -> t = wt*32 + 8*(m>>2) + 4T + (m&3)
    // output rows (quad,r): t = wt*32 + 8*quad + 4T + r -> (T0,T1) = 16x16x32 A-frag
    int kbase[2], kx0[2], kx1[2];
#pragma unroll
    for (int T = 0; T < 2; ++T) {
        const int R = wt * 32 + ((l16 >> 2) << 3) + (T << 2) + (l16 & 3);
        const int fR = (R & 7) ^ ((R >> 2) & 7);  // matches staging swizzle fK
        kbase[T] = R * 64;
        kx0[T] = (quad ^ fR) << 3;
        kx1[T] = ((4 + quad) ^ fR) << 3;
    }

    floatx4 oacc[4][4];  // [mi][dt] partial O over this wave's t-half
#pragma unroll
    for (int mi = 0; mi < 4; ++mi)
#pragma unroll
        for (int dt = 0; dt < 4; ++dt) { floatx4 zz = {0.f,0.f,0.f,0.f}; oacc[mi][dt] = zz; }
    floatx4 sacc[4];  // psum partial via ones-MFMA (row-sum, replicated over l16)
#pragma unroll
    for (int mi = 0; mi < 4; ++mi) { floatx4 zz = {0.f,0.f,0.f,0.f}; sacc[mi] = zz; }
    const floatx4 z4 = {0.f, 0.f, 0.f, 0.f};
    const short ob = (short)0x3F80;  // bf16 1.0
    const short8 ones8 = {ob, ob, ob, ob, ob, ob, ob, ob};

    // stage one 64-t tile; 256 threads, 2 psi passes; 4 gload_lds/thread
    auto stage = [&](int buf, int t0) {
#pragma unroll
        for (int psi = 0; psi < 2; ++psi) {
            const int r = psi * 32 + wave * 8 + (lane >> 3);
            const int j = lane & 7;
            const int cK = j ^ ((r & 7) ^ ((r >> 2) & 7));  // fK swizzle
            const int cV = j ^ (r & 7);
            gload_lds16(Kh + (size_t)(t0 + r) * HD + cK * 8,
                        &smem[buf * 4096 + psi * 2048 + wave * 512]);
            gload_lds16(Vh + (size_t)r * SEQ + t0 + cV * 8,
                        &smem[8192 + buf * 4096 + psi * 2048 + wave * 512]);
        }
    };

    stage(0, 0);
    int buf = 0;
    for (int t0 = 0; t0 < SEQ; t0 += 64) {
        // --- counted-vmcnt barrier schedule (T4, m201 pattern) ---
        __builtin_amdgcn_s_barrier();
        __builtin_amdgcn_sched_barrier(0);
        if (t0 + 64 < SEQ) {
            stage(buf ^ 1, t0 + 64);  // 4 gload_lds issued, stay in flight
            asm volatile("s_waitcnt vmcnt(4)" ::: "memory");
        } else {
            asm volatile("s_waitcnt vmcnt(0)" ::: "memory");
        }
        __builtin_amdgcn_s_barrier();
        __builtin_amdgcn_sched_barrier(0);

        const unsigned short* sKs  = &smem[buf * 4096];
        const unsigned short* sVTs = &smem[8192 + buf * 4096];

        // fragment reads: K half (4 b128) + V half (4 b128), shared across all mi
        short8 bK0[2], bK1[2];
#pragma unroll
        for (int T = 0; T < 2; ++T) {
            bK0[T] = *(const short8*)&sKs[kbase[T] + kx0[T]];
            bK1[T] = *(const short8*)&sKs[kbase[T] + kx1[T]];
        }
        short8 bv8[4];
#pragma unroll
        for (int dt = 0; dt < 4; ++dt)
            bv8[dt] = *(const short8*)&sVTs[(dt * 16 + l16) * 64 + (((wt * 4 + quad) ^ xm) << 3)];

        // batched QK phase: 8 indep MFMA then 8 accumulating (R3-style ILP)
        floatx4 stf[4][2];
#pragma unroll
        for (int mi = 0; mi < 4; ++mi)
#pragma unroll
            for (int T = 0; T < 2; ++T)
                stf[mi][T] = __builtin_amdgcn_mfma_f32_16x16x32_bf16(bK0[T], qf[mi][0], z4, 0, 0, 0);
#pragma unroll
        for (int mi = 0; mi < 4; ++mi)
#pragma unroll
            for (int T = 0; T < 2; ++T)
                stf[mi][T] = __builtin_amdgcn_mfma_f32_16x16x32_bf16(bK1[T], qf[mi][1], stf[mi][T], 0, 0, 0);

        // batched exp/pack phase; order [T0.r0-3, T1.r0-3] == k = 8*quad+0..7
        short8 paf[4];
#pragma unroll
        for (int mi = 0; mi < 4; ++mi) {
            const float e0 = __builtin_amdgcn_exp2f(stf[mi][0][0]);
            const float e1 = __builtin_amdgcn_exp2f(stf[mi][0][1]);
            const float e2 = __builtin_amdgcn_exp2f(stf[mi][0][2]);
            const float e3 = __builtin_amdgcn_exp2f(stf[mi][0][3]);
            const float e4 = __builtin_amdgcn_exp2f(stf[mi][1][0]);
            const float e5 = __builtin_amdgcn_exp2f(stf[mi][1][1]);
            const float e6 = __builtin_amdgcn_exp2f(stf[mi][1][2]);
            const float e7 = __builtin_amdgcn_exp2f(stf[mi][1][3]);
            union { uint4 u; short8 s; } cv;
            cv.u.x = pk_bf2t(e0, e1);
            cv.u.y = pk_bf2t(e2, e3);
            cv.u.z = pk_bf2t(e4, e5);
            cv.u.w = pk_bf2t(e6, e7);
            paf[mi] = cv.s;
        }

        // batched PV phase: psum on MFMA pipe, then O accumulate
#pragma unroll
        for (int mi = 0; mi < 4; ++mi) {
            sacc[mi] = __builtin_amdgcn_mfma_f32_16x16x32_bf16(paf[mi], ones8, sacc[mi], 0, 0, 0);
#pragma unroll
            for (int dt = 0; dt < 4; ++dt)
                oacc[mi][dt] = __builtin_amdgcn_mfma_f32_16x16x32_bf16(paf[mi], bv8[dt], oacc[mi][dt], 0, 0, 0);
        }
        buf ^= 1;
    }

    // ---- cross-wt reduce (R5-validated): O = O_0 + O_1, psum likewise ----
    __syncthreads();  // all staging reads done; safe to alias smem
    float* sRed = (float*)smem;  // [wq][ (mi*4+dt)*256 + (quad*4+r)*16 + l16 ]
    if (wt == 1) {
#pragma unroll
        for (int mi = 0; mi < 4; ++mi) {
#pragma unroll
            for (int dt = 0; dt < 4; ++dt)
#pragma unroll
                for (int r = 0; r < 4; ++r)
                    sRed[wq * 4096 + (mi * 4 + dt) * 256 + (quad * 4 + r) * 16 + l16] = oacc[mi][dt][r];
            if (l16 == 0) {
#pragma unroll
                for (int r = 0; r < 4; ++r)
                    sPS[wq * 64 + mi * 16 + quad * 4 + r] = sacc[mi][r];
            }
        }
    }
    __syncthreads();
    if (wt == 0) {
        const int b = bh >> 3, h = bh & 7;
#pragma unroll
        for (int mi = 0; mi < 4; ++mi) {
            float inv[4];
#pragma unroll
            for (int r = 0; r < 4; ++r)
                inv[r] = 1.0f / (sacc[mi][r] + sPS[wq * 64 + mi * 16 + quad * 4 + r]);
#pragma unroll
            for (int dt = 0; dt < 4; ++dt)
#pragma unroll
                for (int r = 0; r < 4; ++r) {
                    const float o = oacc[mi][dt][r] +
                        sRed[wq * 4096 + (mi * 4 + dt) * 256 + (quad * 4 + r) * 16 + l16];
                    const int s = q0 + wq * 64 + mi * 16 + quad * 4 + r;
                    Oout[((size_t)b * SEQ + s) * EMB + h * HD + dt * 16 + l16] = f2bf_rne(o * inv[r]);
                }
        }
    }
}

// ---------------- output projection, 64x128, counted vmcnt, float4 epilogue ----------------
__global__ __launch_bounds__(256) void outproj_kernel(
    const unsigned short* __restrict__ Ain, const unsigned short* __restrict__ wob,
    const float* __restrict__ bias, const float* __restrict__ X,
    float* __restrict__ out)
{
    __shared__ unsigned short smem[24576];  // sA[2][4096] @0 | sB[2][8192] @8192 (48KB)
                                            // epilogue ct aliases: 64x132 f32 = 33.8KB
    unsigned short* sA = smem;
    unsigned short* sB = smem + 8192;

    const int tid = threadIdx.x, wave = tid >> 6, lane = tid & 63;
    const int quad = lane >> 4, l16 = lane & 15;
    const int wm = wave >> 1, wn = wave & 1;
    const int row0 = blockIdx.x * 64, col0 = blockIdx.y * 128;

    const unsigned short* A = Ain + (size_t)row0 * EMB;
    const unsigned short* Bm = wob + (size_t)col0 * EMB;

    // issues exactly 6 gload_lds per thread -> vmcnt counts 6 per stage
    auto stage = [&](int buf, int k0) {
#pragma unroll
        for (int it = 0; it < 2; ++it) {
            const int s = it * 256 + tid;
            const int row = s >> 3, cg = (s & 7) ^ (row & 7);
            gload_lds16(A + (size_t)row * EMB + k0 + cg * 8, &sA[buf * 4096 + (it * 256 + wave * 64) * 8]);
        }
#pragma unroll
        for (int it = 0; it < 4; ++it) {
            const int s = it * 256 + tid;
            const int row = s >> 3, cg = (s & 7) ^ (row & 7);
            gload_lds16(Bm + (size_t)row * EMB + k0 + cg * 8, &sB[buf * 8192 + (it * 256 + wave * 64) * 8]);
        }
    };

    floatx4 acc[2][4];
#pragma unroll
    for (int mi = 0; mi < 2; ++mi)
#pragma unroll
        for (int ni = 0; ni < 4; ++ni) { floatx4 zz = {0.f,0.f,0.f,0.f}; acc[mi][ni] = zz; }

    stage(0, 0);
    int buf = 0;
    for (int k0 = 0; k0 < EMB; k0 += 64) {
        __builtin_amdgcn_s_barrier();
        __builtin_amdgcn_sched_barrier(0);
        if (k0 + 64 < EMB) {
            stage(buf ^ 1, k0 + 64);
            asm volatile("s_waitcnt vmcnt(6)" ::: "memory");
        } else {
            asm volatile("s_waitcnt vmcnt(0)" ::: "memory");
        }
        __builtin_amdgcn_s_barrier();
        __builtin_amdgcn_sched_barrier(0);
#pragma unroll
        for (int kk = 0; kk < 2; ++kk) {
            short8 a[2], b[4];
#pragma unroll
            for (int mi = 0; mi < 2; ++mi)
                a[mi] = *(const short8*)&sA[buf * 4096 + (wm * 32 + mi * 16 + l16) * 64 + (((kk * 4 + quad) ^ (l16 & 7)) << 3)];
#pragma unroll
            for (int ni = 0; ni < 4; ++ni)
                b[ni] = *(const short8*)&sB[buf * 8192 + (wn * 64 + ni * 16 + l16) * 64 + (((kk * 4 + quad) ^ (l16 & 7)) << 3)];
#pragma unroll
            for (int mi = 0; mi < 2; ++mi)
#pragma unroll
                for (int ni = 0; ni < 4; ++ni)
                    acc[mi][ni] = __builtin_amdgcn_mfma_f32_16x16x32_bf16(a[mi], b[ni], acc[mi][ni], 0, 0, 0);
        }
        buf ^= 1;
    }

    // ---- epilogue: transpose via ct[64][132] f32 (bias folded), then
    // fully-coalesced float4 X-add + float4 stores (2 rows x 512B per wave) ----
    __syncthreads();
    float* ct = (float*)smem;  // 64*132*4 = 33.8 KB <= 48 KB
#pragma unroll
    for (int mi = 0; mi < 2; ++mi)
#pragma unroll
        for (int ni = 0; ni < 4; ++ni) {
            const int n = wn * 64 + ni * 16 + l16;
            const float bs = bias[col0 + n];
#pragma unroll
            for (int r = 0; r < 4; ++r) {
                const int m = wm * 32 + mi * 16 + quad * 4 + r;
                ct[m * 132 + n] = acc[mi][ni][r] + bs;
            }
        }
    __syncthreads();
#pragma unroll
    for (int it = 0; it < 8; ++it) {
        const int idx = it * 256 + tid;
        const int row = idx >> 5, seg = idx & 31;  // 64 rows x 32 float4 segs
        const float4 cv = *(const float4*)&ct[row * 132 + seg * 4];
        const size_t gidx = (size_t)(row0 + row) * EMB + col0 + seg * 4;
        const float4 xv = *(const float4*)&X[gidx];
        float4 ov;
        ov.x = cv.x + xv.x; ov.y = cv.y + xv.y;
        ov.z = cv.z + xv.z; ov.w = cv.w + xv.w;
        *(float4*)&out[gidx] = ov;
    }
}

extern "C" void kernel_launch(void* const* d_in, const int* in_sizes, int n_in,
                              void* d_out, int out_size, void* d_ws, size_t ws_size,
                              hipStream_t stream) {
    const float* x  = (const float*)d_in[0];
    const float* Wq = (const float*)d_in[1];
    const float* bq = (const float*)d_in[2];
    const float* Wk = (const float*)d_in[3];
    const float* bk = (const float*)d_in[4];
    const float* Wv = (const float*)d_in[5];
    const float* bv = (const float*)d_in[6];
    const float* Wo = (const float*)d_in[7];
    const float* bo = (const float*)d_in[8];
    float* out = (float*)d_out;

    const size_t SZ = (size_t)MROWS * EMB;
    unsigned short* wsXB = (unsigned short*)d_ws;  // also O (attn output)
    unsigned short* wsWB = wsXB + SZ;
    unsigned short* wsQ  = wsWB + 4 * 262144;
    unsigned short* wsK  = wsQ + SZ;
    unsigned short* wsVT = wsK + SZ;

    convert_kernel<<<2560, 256, 0, stream>>>(x, Wq, Wk, Wv, Wo, wsXB, wsWB);
    qkv_kernel<<<dim3(MROWS / 128, EMB / 128, 3), 256, 0, stream>>>(
        wsXB, wsWB, bq, bk, bv, wsQ, wsK, wsVT);
    attn_kernel<<<dim3(2 * NH, SEQ / 128), 256, 0, stream>>>(wsQ, wsK, wsVT, wsXB);
    outproj_kernel<<<dim3(MROWS / 64, EMB / 128), 256, 0, stream>>>(
        wsXB, wsWB + 3 * 262144, bo, x, out);
}

// Round 15
// 182.093 us; speedup vs baseline: 1.0279x; 1.0279x over previous
//
#include <hip/hip_runtime.h>
#include <hip/hip_bf16.h>

// MHA: B=2, S=4096, E=512, H=8, D=64. fp32 in/out, bf16 MFMA internally.
// ws (shorts): XB/O [8192*512] | WB [4*512*512] | Q | K | VT
// Q pre-scaled by log2(e)/sqrt(D).
// R15 attn = R14 (wq x wt, W_q=64, batched phases, counted vmcnt; best attn
// 75.8-76.2us) + ONE-TILE SOFTWARE PIPELINE (T15): PV of tile i-1 computed
// inside iteration i, fully independent of QK[i]/exp[i] -> scheduler can
// fill the MFMA pipe through the exp phase. pafP/bvP register-held across
// one iteration (V must be reg-held: tile i-1's LDS buffer is overwritten
// by tile i+1's staging). pafP zero-init -> first PV adds zeros (branchless
// prologue); final PV after loop. R14 falsified the LDS-throughput theory
// (reads halved, wall -2%): attn is dependency-latency-bound at 2 w/SIMD.
// Permuted K-row map within wt's 32-t half: tile T row m holds
// t = wt*32 + 8*(m>>2) + 4*T + (m&3) -> (T0,T1) = 16x16x32 A-frag ->
// full-rate K=32 PV. K LDS swizzle f(r)=(r&7)^((r>>2)&7); V chunk c^=(r&7).
// psum via ones-MFMA (row-sum replicated over l16; bias cancels in ratio).
// convert/qkv/outproj = R13/R10 verbatim. Ledger: R11 fusion -9us,
// R12 BK=32 -13us (both reverted); TLP/t-split/drain all falsified.

typedef __attribute__((ext_vector_type(8))) short short8;
typedef __attribute__((ext_vector_type(4))) short short4v;
typedef __attribute__((ext_vector_type(4))) float floatx4;
typedef __attribute__((ext_vector_type(2))) float floatx2;

#define SEQ 4096
#define EMB 512
#define NH 8
#define HD 64
#define MROWS 8192
#define SC2 0.18033688011112042f  // log2(e)/sqrt(64)

__device__ inline unsigned short f2bf_rne(float f) {
    union { float f; unsigned int u; } c; c.f = f;
    unsigned int u = c.u;
    return (unsigned short)((u + 0x7FFFu + ((u >> 16) & 1u)) >> 16);
}

__device__ inline short8 load8f(const float* __restrict__ p) {
    float4 a = *(const float4*)p;
    float4 b = *(const float4*)(p + 4);
    short8 r;
    r[0] = (short)f2bf_rne(a.x); r[1] = (short)f2bf_rne(a.y);
    r[2] = (short)f2bf_rne(a.z); r[3] = (short)f2bf_rne(a.w);
    r[4] = (short)f2bf_rne(b.x); r[5] = (short)f2bf_rne(b.y);
    r[6] = (short)f2bf_rne(b.z); r[7] = (short)f2bf_rne(b.w);
    return r;
}

__device__ inline void gload_lds16(const unsigned short* g, unsigned short* l) {
    __builtin_amdgcn_global_load_lds(
        (__attribute__((address_space(1))) void*)(void*)g,
        (__attribute__((address_space(3))) void*)l,
        16, 0, 0);
}

// pack 2 f32 -> 2 bf16, round-half-up (epilogue-quality)
__device__ inline unsigned int pk_bf2(float a, float b) {
    union { float f; unsigned int u; } ca, cb; ca.f = a; cb.f = b;
    return __builtin_amdgcn_perm(cb.u + 0x8000u, ca.u + 0x8000u, 0x07060302u);
}

// pack 2 f32 -> 2 bf16, truncating (P-matrix: positive values, <=0.2% bias)
__device__ inline unsigned int pk_bf2t(float a, float b) {
    union { float f; unsigned int u; } ca, cb; ca.f = a; cb.f = b;
    return __builtin_amdgcn_perm(cb.u, ca.u, 0x07060302u);
}

// ---------------- fp32 -> bf16 pre-convert ----------------
__global__ __launch_bounds__(256) void convert_kernel(
    const float* __restrict__ x, const float* __restrict__ Wq,
    const float* __restrict__ Wk, const float* __restrict__ Wv,
    const float* __restrict__ Wo, unsigned short* __restrict__ xb,
    unsigned short* __restrict__ wb)
{
    const size_t i8 = ((size_t)blockIdx.x * 256 + threadIdx.x) * 8;
    const float* src; unsigned short* dst;
    if (i8 < (size_t)MROWS * EMB) { src = x + i8; dst = xb + i8; }
    else {
        size_t j = i8 - (size_t)MROWS * EMB;
        int w = (int)(j >> 18); size_t off = j & 262143;
        src = (w == 0 ? Wq : w == 1 ? Wk : w == 2 ? Wv : Wo) + off;
        dst = wb + (size_t)w * 262144 + off;
    }
    *(short8*)dst = load8f(src);
}

// ---------------- QKV projection, 128x128, BK=64, dbuf, counted vmcnt ----------------
// z=0 -> Q [b,h,s,d] scaled SC2; z=1 -> K [b,h,s,d]; z=2 -> V^T [b,h,d,s]
__global__ __launch_bounds__(256) void qkv_kernel(
    const unsigned short* __restrict__ xb, const unsigned short* __restrict__ wb,
    const float* __restrict__ bq, const float* __restrict__ bk,
    const float* __restrict__ bv, unsigned short* __restrict__ Qo,
    unsigned short* __restrict__ Ko, unsigned short* __restrict__ VTo)
{
    __shared__ unsigned short smem[32768];  // sA[2][8192] | sB[2][8192]; epilogue ct aliases

    const int tid = threadIdx.x, wave = tid >> 6, lane = tid & 63;
    const int quad = lane >> 4, l16 = lane & 15;
    const int wm = wave >> 1, wn = wave & 1;
    const int row0 = blockIdx.x * 128, col0 = blockIdx.y * 128;
    const int z = blockIdx.z;

    unsigned short* sA = smem;
    unsigned short* sB = smem + 16384;

    const unsigned short* A = xb + (size_t)row0 * EMB;
    const unsigned short* Bm = wb + (size_t)z * 262144 + (size_t)col0 * EMB;
    const float* bias = z == 0 ? bq : z == 1 ? bk : bv;
    unsigned short* out = z == 0 ? Qo : z == 1 ? Ko : VTo;

    // issues exactly 8 gload_lds per thread -> vmcnt counts 8 per stage
    auto stage = [&](int buf, int k0) {
#pragma unroll
        for (int it = 0; it < 4; ++it) {
            const int s = it * 256 + tid;
            const int row = s >> 3, cg = (s & 7) ^ (row & 7);
            const size_t go = (size_t)row * EMB + k0 + cg * 8;
            gload_lds16(A + go, &sA[buf * 8192 + (it * 256 + wave * 64) * 8]);
            gload_lds16(Bm + go, &sB[buf * 8192 + (it * 256 + wave * 64) * 8]);
        }
    };

    floatx4 acc[4][4];
#pragma unroll
    for (int i = 0; i < 4; ++i)
#pragma unroll
        for (int j = 0; j < 4; ++j) { floatx4 zz = {0.f,0.f,0.f,0.f}; acc[i][j] = zz; }

    stage(0, 0);
    int buf = 0;
    for (int k0 = 0; k0 < EMB; k0 += 64) {
        __builtin_amdgcn_s_barrier();
        __builtin_amdgcn_sched_barrier(0);
        if (k0 + 64 < EMB) {
            stage(buf ^ 1, k0 + 64);
            asm volatile("s_waitcnt vmcnt(8)" ::: "memory");
        } else {
            asm volatile("s_waitcnt vmcnt(0)" ::: "memory");
        }
        __builtin_amdgcn_s_barrier();
        __builtin_amdgcn_sched_barrier(0);
#pragma unroll
        for (int kk = 0; kk < 2; ++kk) {
            short8 a[4], b[4];
#pragma unroll
            for (int mi = 0; mi < 4; ++mi)
                a[mi] = *(const short8*)&sA[buf * 8192 + (wm * 64 + mi * 16 + l16) * 64 + (((kk * 4 + quad) ^ (l16 & 7)) << 3)];
#pragma unroll
            for (int ni = 0; ni < 4; ++ni)
                b[ni] = *(const short8*)&sB[buf * 8192 + (wn * 64 + ni * 16 + l16) * 64 + (((kk * 4 + quad) ^ (l16 & 7)) << 3)];
            if (z != 2) {
                // swapped operands -> acc[i][j] = C^T block: rows n (i), cols m (j)
#pragma unroll
                for (int i = 0; i < 4; ++i)
#pragma unroll
                    for (int j = 0; j < 4; ++j)
                        acc[i][j] = __builtin_amdgcn_mfma_f32_16x16x32_bf16(b[i], a[j], acc[i][j], 0, 0, 0);
            } else {
#pragma unroll
                for (int i = 0; i < 4; ++i)
#pragma unroll
                    for (int j = 0; j < 4; ++j)
                        acc[i][j] = __builtin_amdgcn_mfma_f32_16x16x32_bf16(a[i], b[j], acc[i][j], 0, 0, 0);
            }
        }
        buf ^= 1;
    }

    // ---- epilogue: pack b64 into ct[row][132] then coalesced b128 stores ----
    __syncthreads();
    unsigned short* ct = smem;  // 128 x 132 shorts = 33.8 KB (aliases staging)
    const float qs = (z == 0) ? SC2 : 1.0f;
    if (z != 2) {
#pragma unroll
        for (int i = 0; i < 4; ++i) {
            const int n0 = wn * 64 + i * 16 + quad * 4;
            const float4 fb = *(const float4*)&bias[col0 + n0];
#pragma unroll
            for (int j = 0; j < 4; ++j) {
                const int m = wm * 64 + j * 16 + l16;
                ushort4 pk;
                pk.x = f2bf_rne((acc[i][j][0] + fb.x) * qs);
                pk.y = f2bf_rne((acc[i][j][1] + fb.y) * qs);
                pk.z = f2bf_rne((acc[i][j][2] + fb.z) * qs);
                pk.w = f2bf_rne((acc[i][j][3] + fb.w) * qs);
                *(ushort4*)&ct[m * 132 + n0] = pk;
            }
        }
    } else {
#pragma unroll
        for (int j = 0; j < 4; ++j) {
            const int n = wn * 64 + j * 16 + l16;
            const float fb = bias[col0 + n];
#pragma unroll
            for (int i = 0; i < 4; ++i) {
                const int m0 = wm * 64 + i * 16 + quad * 4;
                ushort4 pk;
                pk.x = f2bf_rne(acc[i][j][0] + fb);
                pk.y = f2bf_rne(acc[i][j][1] + fb);
                pk.z = f2bf_rne(acc[i][j][2] + fb);
                pk.w = f2bf_rne(acc[i][j][3] + fb);
                *(ushort4*)&ct[n * 132 + m0] = pk;
            }
        }
    }
    __syncthreads();
#pragma unroll
    for (int it = 0; it < 8; ++it) {
        const int idx = it * 256 + tid;
        const int row = idx >> 4, chunk = idx & 15;
        short8 v = *(const short8*)&ct[row * 132 + chunk * 8];
        size_t addr;
        if (z != 2) {
            const int m_g = row0 + row;
            const int b = m_g >> 12, s = m_g & 4095;
            const int n_g = col0 + chunk * 8;
            const int h = n_g >> 6, d = n_g & 63;
            addr = ((size_t)((b * NH + h) * SEQ + s)) * HD + d;
        } else {
            const int n_g = col0 + row;
            const int h = n_g >> 6, d = n_g & 63;
            const int m_g = row0 + chunk * 8;
            const int b = m_g >> 12, s0 = m_g & 4095;
            addr = ((size_t)((b * NH + h) * HD + d)) * SEQ + s0;
        }
        *(short8*)&out[addr] = v;
    }
}

// ---------------- flash attention: 2q x 2t waves, W_q=64, 1-tile pipeline, counted vmcnt ----------------
// grid (bh, q-tile 128): same-bh blocks land on same XCD (stride 16 % 8 == 0) -> L2 reuse
__global__ __launch_bounds__(256, 2) void attn_kernel(
    const unsigned short* __restrict__ Q, const unsigned short* __restrict__ K,
    const unsigned short* __restrict__ VT, unsigned short* __restrict__ Oout)
{
    // staging: sK[buf] @ [buf*4096), sVT[buf] @ [8192+buf*4096) (shorts, 32KB)
    // cross-wt reduce aliases as float[8192]: per-wq 4096-float region
    __shared__ unsigned short smem[16384];
    __shared__ float sPS[128];  // [wq*64 + q] psum partials from wt=1

    const int tid = threadIdx.x, wave = tid >> 6, lane = tid & 63;
    const int quad = lane >> 4, l16 = lane & 15;
    const int wq = wave >> 1, wt = wave & 1;
    const int bh = blockIdx.x, q0 = blockIdx.y * 128;
    const int xm = l16 & 7;

    const unsigned short* Qh = Q + (size_t)bh * SEQ * HD;
    const unsigned short* Kh = K + (size_t)bh * SEQ * HD;
    const unsigned short* Vh = VT + (size_t)bh * HD * SEQ;

    // this wave's 64 q-rows (q-group wq), mi = 0..3
    short8 qf[4][2];  // [mi][kk]
#pragma unroll
    for (int mi = 0; mi < 4; ++mi)
#pragma unroll
        for (int kk = 0; kk < 2; ++kk)
            qf[mi][kk] = *(const short8*)(Qh + (size_t)(q0 + wq * 64 + mi * 16 + l16) * HD + kk * 32 + quad * 8);

    // permuted K-row map for t-half wt: tile T, A-row m -> t = wt*32 + 8*(m>>2) + 4T + (m&3)
    // output rows (quad,r): t = wt*32 + 8*quad + 4T + r -> (T0,T1) = 16x16x32 A-frag
    int kbase[2], kx0[2], kx1[2];
#pragma unroll
    for (int T = 0; T < 2; ++T) {
        const int R = wt * 32 + ((l16 >> 2) << 3) + (T << 2) + (l16 & 3);
        const int fR = (R & 7) ^ ((R >> 2) & 7);  // matches staging swizzle fK
        kbase[T] = R * 64;
        kx0[T] = (quad ^ fR) << 3;
        kx1[T] = ((4 + quad) ^ fR) << 3;
    }

    floatx4 oacc[4][4];  // [mi][dt] partial O over this wave's t-half
#pragma unroll
    for (int mi = 0; mi < 4; ++mi)
#pragma unroll
        for (int dt = 0; dt < 4; ++dt) { floatx4 zz = {0.f,0.f,0.f,0.f}; oacc[mi][dt] = zz; }
    floatx4 sacc[4];  // psum partial via ones-MFMA (row-sum, replicated over l16)
#pragma unroll
    for (int mi = 0; mi < 4; ++mi) { floatx4 zz = {0.f,0.f,0.f,0.f}; sacc[mi] = zz; }
    const floatx4 z4 = {0.f, 0.f, 0.f, 0.f};
    const short ob = (short)0x3F80;  // bf16 1.0
    const short8 ones8 = {ob, ob, ob, ob, ob, ob, ob, ob};

    // pipeline registers: P-frags and V-frags of the PREVIOUS tile.
    // pafP zero-init -> first PV contributes exact zeros (branchless prologue).
    short8 pafP[4], bvP[4];
    {
        const short8 zz8 = {0, 0, 0, 0, 0, 0, 0, 0};
#pragma unroll
        for (int i = 0; i < 4; ++i) { pafP[i] = zz8; bvP[i] = zz8; }
    }

    // stage one 64-t tile; 256 threads, 2 psi passes; 4 gload_lds/thread
    auto stage = [&](int buf, int t0) {
#pragma unroll
        for (int psi = 0; psi < 2; ++psi) {
            const int r = psi * 32 + wave * 8 + (lane >> 3);
            const int j = lane & 7;
            const int cK = j ^ ((r & 7) ^ ((r >> 2) & 7));  // fK swizzle
            const int cV = j ^ (r & 7);
            gload_lds16(Kh + (size_t)(t0 + r) * HD + cK * 8,
                        &smem[buf * 4096 + psi * 2048 + wave * 512]);
            gload_lds16(Vh + (size_t)r * SEQ + t0 + cV * 8,
                        &smem[8192 + buf * 4096 + psi * 2048 + wave * 512]);
        }
    };

    stage(0, 0);
    int buf = 0;
    for (int t0 = 0; t0 < SEQ; t0 += 64) {
        // --- counted-vmcnt barrier schedule (T4, m201 pattern) ---
        __builtin_amdgcn_s_barrier();
        __builtin_amdgcn_sched_barrier(0);
        if (t0 + 64 < SEQ) {
            stage(buf ^ 1, t0 + 64);  // 4 gload_lds issued, stay in flight
            asm volatile("s_waitcnt vmcnt(4)" ::: "memory");
        } else {
            asm volatile("s_waitcnt vmcnt(0)" ::: "memory");
        }
        __builtin_amdgcn_s_barrier();
        __builtin_amdgcn_sched_barrier(0);

        const unsigned short* sKs  = &smem[buf * 4096];
        const unsigned short* sVTs = &smem[8192 + buf * 4096];

        // current tile fragment reads: K half (4 b128) + V half (4 b128)
        short8 bK0[2], bK1[2];
#pragma unroll
        for (int T = 0; T < 2; ++T) {
            bK0[T] = *(const short8*)&sKs[kbase[T] + kx0[T]];
            bK1[T] = *(const short8*)&sKs[kbase[T] + kx1[T]];
        }
        short8 bv8[4];
#pragma unroll
        for (int dt = 0; dt < 4; ++dt)
            bv8[dt] = *(const short8*)&sVTs[(dt * 16 + l16) * 64 + (((wt * 4 + quad) ^ xm) << 3)];

        // QK phase for CURRENT tile (16 MFMA, 2-deep chains)
        floatx4 stf[4][2];
#pragma unroll
        for (int mi = 0; mi < 4; ++mi)
#pragma unroll
            for (int T = 0; T < 2; ++T)
                stf[mi][T] = __builtin_amdgcn_mfma_f32_16x16x32_bf16(bK0[T], qf[mi][0], z4, 0, 0, 0);
#pragma unroll
        for (int mi = 0; mi < 4; ++mi)
#pragma unroll
            for (int T = 0; T < 2; ++T)
                stf[mi][T] = __builtin_amdgcn_mfma_f32_16x16x32_bf16(bK1[T], qf[mi][1], stf[mi][T], 0, 0, 0);

        // PV phase for PREVIOUS tile (20 MFMA) -- independent of stf/exp;
        // scheduler interleaves these with the exp/pack VALU chain below.
#pragma unroll
        for (int mi = 0; mi < 4; ++mi) {
            sacc[mi] = __builtin_amdgcn_mfma_f32_16x16x32_bf16(pafP[mi], ones8, sacc[mi], 0, 0, 0);
#pragma unroll
            for (int dt = 0; dt < 4; ++dt)
                oacc[mi][dt] = __builtin_amdgcn_mfma_f32_16x16x32_bf16(pafP[mi], bvP[dt], oacc[mi][dt], 0, 0, 0);
        }

        // exp/pack for CURRENT tile -> pafP (WAR on pafP: PV above reads at
        // issue, pack writes after); order [T0.r0-3,T1.r0-3] == k=8*quad+0..7
#pragma unroll
        for (int mi = 0; mi < 4; ++mi) {
            const float e0 = __builtin_amdgcn_exp2f(stf[mi][0][0]);
            const float e1 = __builtin_amdgcn_exp2f(stf[mi][0][1]);
            const float e2 = __builtin_amdgcn_exp2f(stf[mi][0][2]);
            const float e3 = __builtin_amdgcn_exp2f(stf[mi][0][3]);
            const float e4 = __builtin_amdgcn_exp2f(stf[mi][1][0]);
            const float e5 = __builtin_amdgcn_exp2f(stf[mi][1][1]);
            const float e6 = __builtin_amdgcn_exp2f(stf[mi][1][2]);
            const float e7 = __builtin_amdgcn_exp2f(stf[mi][1][3]);
            union { uint4 u; short8 s; } cv;
            cv.u.x = pk_bf2t(e0, e1);
            cv.u.y = pk_bf2t(e2, e3);
            cv.u.z = pk_bf2t(e4, e5);
            cv.u.w = pk_bf2t(e6, e7);
            pafP[mi] = cv.s;
        }
        // carry current V-frags for next iteration's PV
#pragma unroll
        for (int dt = 0; dt < 4; ++dt) bvP[dt] = bv8[dt];

        buf ^= 1;
    }

    // drain pipeline: PV for the last tile
#pragma unroll
    for (int mi = 0; mi < 4; ++mi) {
        sacc[mi] = __builtin_amdgcn_mfma_f32_16x16x32_bf16(pafP[mi], ones8, sacc[mi], 0, 0, 0);
#pragma unroll
        for (int dt = 0; dt < 4; ++dt)
            oacc[mi][dt] = __builtin_amdgcn_mfma_f32_16x16x32_bf16(pafP[mi], bvP[dt], oacc[mi][dt], 0, 0, 0);
    }

    // ---- cross-wt reduce (R5-validated): O = O_0 + O_1, psum likewise ----
    __syncthreads();  // all staging reads done; safe to alias smem
    float* sRed = (float*)smem;  // [wq][ (mi*4+dt)*256 + (quad*4+r)*16 + l16 ]
    if (wt == 1) {
#pragma unroll
        for (int mi = 0; mi < 4; ++mi) {
#pragma unroll
            for (int dt = 0; dt < 4; ++dt)
#pragma unroll
                for (int r = 0; r < 4; ++r)
                    sRed[wq * 4096 + (mi * 4 + dt) * 256 + (quad * 4 + r) * 16 + l16] = oacc[mi][dt][r];
            if (l16 == 0) {
#pragma unroll
                for (int r = 0; r < 4; ++r)
                    sPS[wq * 64 + mi * 16 + quad * 4 + r] = sacc[mi][r];
            }
        }
    }
    __syncthreads();
    if (wt == 0) {
        const int b = bh >> 3, h = bh & 7;
#pragma unroll
        for (int mi = 0; mi < 4; ++mi) {
            float inv[4];
#pragma unroll
            for (int r = 0; r < 4; ++r)
                inv[r] = 1.0f / (sacc[mi][r] + sPS[wq * 64 + mi * 16 + quad * 4 + r]);
#pragma unroll
            for (int dt = 0; dt < 4; ++dt)
#pragma unroll
                for (int r = 0; r < 4; ++r) {
                    const float o = oacc[mi][dt][r] +
                        sRed[wq * 4096 + (mi * 4 + dt) * 256 + (quad * 4 + r) * 16 + l16];
                    const int s = q0 + wq * 64 + mi * 16 + quad * 4 + r;
                    Oout[((size_t)b * SEQ + s) * EMB + h * HD + dt * 16 + l16] = f2bf_rne(o * inv[r]);
                }
        }
    }
}

// ---------------- output projection, 64x128, counted vmcnt, float4 epilogue ----------------
__global__ __launch_bounds__(256) void outproj_kernel(
    const unsigned short* __restrict__ Ain, const unsigned short* __restrict__ wob,
    const float* __restrict__ bias, const float* __restrict__ X,
    float* __restrict__ out)
{
    __shared__ unsigned short smem[24576];  // sA[2][4096] @0 | sB[2][8192] @8192 (48KB)
                                            // epilogue ct aliases: 64x132 f32 = 33.8KB
    unsigned short* sA = smem;
    unsigned short* sB = smem + 8192;

    const int tid = threadIdx.x, wave = tid >> 6, lane = tid & 63;
    const int quad = lane >> 4, l16 = lane & 15;
    const int wm = wave >> 1, wn = wave & 1;
    const int row0 = blockIdx.x * 64, col0 = blockIdx.y * 128;

    const unsigned short* A = Ain + (size_t)row0 * EMB;
    const unsigned short* Bm = wob + (size_t)col0 * EMB;

    // issues exactly 6 gload_lds per thread -> vmcnt counts 6 per stage
    auto stage = [&](int buf, int k0) {
#pragma unroll
        for (int it = 0; it < 2; ++it) {
            const int s = it * 256 + tid;
            const int row = s >> 3, cg = (s & 7) ^ (row & 7);
            gload_lds16(A + (size_t)row * EMB + k0 + cg * 8, &sA[buf * 4096 + (it * 256 + wave * 64) * 8]);
        }
#pragma unroll
        for (int it = 0; it < 4; ++it) {
            const int s = it * 256 + tid;
            const int row = s >> 3, cg = (s & 7) ^ (row & 7);
            gload_lds16(Bm + (size_t)row * EMB + k0 + cg * 8, &sB[buf * 8192 + (it * 256 + wave * 64) * 8]);
        }
    };

    floatx4 acc[2][4];
#pragma unroll
    for (int mi = 0; mi < 2; ++mi)
#pragma unroll
        for (int ni = 0; ni < 4; ++ni) { floatx4 zz = {0.f,0.f,0.f,0.f}; acc[mi][ni] = zz; }

    stage(0, 0);
    int buf = 0;
    for (int k0 = 0; k0 < EMB; k0 += 64) {
        __builtin_amdgcn_s_barrier();
        __builtin_amdgcn_sched_barrier(0);
        if (k0 + 64 < EMB) {
            stage(buf ^ 1, k0 + 64);
            asm volatile("s_waitcnt vmcnt(6)" ::: "memory");
        } else {
            asm volatile("s_waitcnt vmcnt(0)" ::: "memory");
        }
        __builtin_amdgcn_s_barrier();
        __builtin_amdgcn_sched_barrier(0);
#pragma unroll
        for (int kk = 0; kk < 2; ++kk) {
            short8 a[2], b[4];
#pragma unroll
            for (int mi = 0; mi < 2; ++mi)
                a[mi] = *(const short8*)&sA[buf * 4096 + (wm * 32 + mi * 16 + l16) * 64 + (((kk * 4 + quad) ^ (l16 & 7)) << 3)];
#pragma unroll
            for (int ni = 0; ni < 4; ++ni)
                b[ni] = *(const short8*)&sB[buf * 8192 + (wn * 64 + ni * 16 + l16) * 64 + (((kk * 4 + quad) ^ (l16 & 7)) << 3)];
#pragma unroll
            for (int mi = 0; mi < 2; ++mi)
#pragma unroll
                for (int ni = 0; ni < 4; ++ni)
                    acc[mi][ni] = __builtin_amdgcn_mfma_f32_16x16x32_bf16(a[mi], b[ni], acc[mi][ni], 0, 0, 0);
        }
        buf ^= 1;
    }

    // ---- epilogue: transpose via ct[64][132] f32 (bias folded), then
    // fully-coalesced float4 X-add + float4 stores (2 rows x 512B per wave) ----
    __syncthreads();
    float* ct = (float*)smem;  // 64*132*4 = 33.8 KB <= 48 KB
#pragma unroll
    for (int mi = 0; mi < 2; ++mi)
#pragma unroll
        for (int ni = 0; ni < 4; ++ni) {
            const int n = wn * 64 + ni * 16 + l16;
            const float bs = bias[col0 + n];
#pragma unroll
            for (int r = 0; r < 4; ++r) {
                const int m = wm * 32 + mi * 16 + quad * 4 + r;
                ct[m * 132 + n] = acc[mi][ni][r] + bs;
            }
        }
    __syncthreads();
#pragma unroll
    for (int it = 0; it < 8; ++it) {
        const int idx = it * 256 + tid;
        const int row = idx >> 5, seg = idx & 31;  // 64 rows x 32 float4 segs
        const float4 cv = *(const float4*)&ct[row * 132 + seg * 4];
        const size_t gidx = (size_t)(row0 + row) * EMB + col0 + seg * 4;
        const float4 xv = *(const float4*)&X[gidx];
        float4 ov;
        ov.x = cv.x + xv.x; ov.y = cv.y + xv.y;
        ov.z = cv.z + xv.z; ov.w = cv.w + xv.w;
        *(float4*)&out[gidx] = ov;
    }
}

extern "C" void kernel_launch(void* const* d_in, const int* in_sizes, int n_in,
                              void* d_out, int out_size, void* d_ws, size_t ws_size,
                              hipStream_t stream) {
    const float* x  = (const float*)d_in[0];
    const float* Wq = (const float*)d_in[1];
    const float* bq = (const float*)d_in[2];
    const float* Wk = (const float*)d_in[3];
    const float* bk = (const float*)d_in[4];
    const float* Wv = (const float*)d_in[5];
    const float* bv = (const float*)d_in[6];
    const float* Wo = (const float*)d_in[7];
    const float* bo = (const float*)d_in[8];
    float* out = (float*)d_out;

    const size_t SZ = (size_t)MROWS * EMB;
    unsigned short* wsXB = (unsigned short*)d_ws;  // also O (attn output)
    unsigned short* wsWB = wsXB + SZ;
    unsigned short* wsQ  = wsWB + 4 * 262144;
    unsigned short* wsK  = wsQ + SZ;
    unsigned short* wsVT = wsK + SZ;

    convert_kernel<<<2560, 256, 0, stream>>>(x, Wq, Wk, Wv, Wo, wsXB, wsWB);
    qkv_kernel<<<dim3(MROWS / 128, EMB / 128, 3), 256, 0, stream>>>(
        wsXB, wsWB, bq, bk, bv, wsQ, wsK, wsVT);
    attn_kernel<<<dim3(2 * NH, SEQ / 128), 256, 0, stream>>>(wsQ, wsK, wsVT, wsXB);
    outproj_kernel<<<dim3(MROWS / 64, EMB / 128), 256, 0, stream>>>(
        wsXB, wsWB + 3 * 262144, bo, x, out);
}